// Round 9
// baseline (259.800 us; speedup 1.0000x reference)
//
#include <hip/hip_runtime.h>
#include <hip/hip_bf16.h>

typedef __attribute__((ext_vector_type(8))) short short8;
typedef __attribute__((ext_vector_type(4))) short short4v;
typedef __attribute__((ext_vector_type(4))) float f32x4;

static constexpr int Nb = 32, Lseq = 2048, Hdim = 1024, Adim = 1024;
// M = Nb*Lseq = 65536 rows; GEMM: [M x A] = keys[M x H] * Wk^T[H x A]

__device__ __forceinline__ short8 pack8(f32x4 a, f32x4 b) {
    short8 r;
#pragma unroll
    for (int i = 0; i < 4; i++) { __bf16 h = (__bf16)a[i]; r[i] = __builtin_bit_cast(short, h); }
#pragma unroll
    for (int i = 0; i < 4; i++) { __bf16 h = (__bf16)b[i]; r[i + 4] = __builtin_bit_cast(short, h); }
    return r;
}

__device__ __forceinline__ float bf2f(short s) {
    return __builtin_bit_cast(float, (unsigned)(unsigned short)s << 16);
}

__device__ __forceinline__ float fast_tanh(float x) {
    float ex = __expf(2.0f * x);
    return 1.0f - 2.0f * __builtin_amdgcn_rcpf(ex + 1.0f);
}

__device__ __forceinline__ void gload_lds16(const void* g, void* l) {
    __builtin_amdgcn_global_load_lds(
        (const __attribute__((address_space(1))) unsigned int*)g,
        (__attribute__((address_space(3))) unsigned int*)l, 16, 0, 0);
}

// ---------------- q = query @ Wq^T : [32 x 1024] (fallback) ----------------
__global__ __launch_bounds__(256) void q_kernel(const float* __restrict__ query,
                                                const float* __restrict__ Wq,
                                                float* __restrict__ qout) {
    int idx = blockIdx.x * 256 + threadIdx.x;
    int n = idx >> 10, a = idx & 1023;
    const f32x4* qr = (const f32x4*)(query + (size_t)n * Hdim);
    const f32x4* wr = (const f32x4*)(Wq + (size_t)a * Hdim);
    float acc = 0.f;
#pragma unroll 8
    for (int i = 0; i < Hdim / 4; i++) {
        f32x4 x = qr[i], y = wr[i];
        acc += x[0] * y[0]; acc += x[1] * y[1]; acc += x[2] * y[2]; acc += x[3] * y[3];
    }
    qout[idx] = acc;
}

// ---------------- fused prep: q (128 blk) | cvt Wk (256 blk) | cvt keys (4096 blk) ----------------
__global__ __launch_bounds__(256) void prep_kernel(const float* __restrict__ query,
                                                   const float* __restrict__ Wq,
                                                   float* __restrict__ qout,
                                                   const float* __restrict__ Wk,
                                                   short* __restrict__ Wkb,
                                                   const float* __restrict__ keys,
                                                   short* __restrict__ keysb) {
    const int bid = blockIdx.x, tid = threadIdx.x;
    if (bid < 128) {
        int idx = bid * 256 + tid;
        int n = idx >> 10, a = idx & 1023;
        const f32x4* qr = (const f32x4*)(query + (size_t)n * Hdim);
        const f32x4* wr = (const f32x4*)(Wq + (size_t)a * Hdim);
        float acc = 0.f;
#pragma unroll 8
        for (int i = 0; i < Hdim / 4; i++) {
            f32x4 x = qr[i], y = wr[i];
            acc += x[0] * y[0]; acc += x[1] * y[1]; acc += x[2] * y[2]; acc += x[3] * y[3];
        }
        qout[idx] = acc;
    } else if (bid < 384) {
        const int n8 = (Adim * Hdim) / 8;
        for (int i = (bid - 128) * 256 + tid; i < n8; i += 256 * 256) {
            f32x4 a = ((const f32x4*)Wk)[i * 2];
            f32x4 b = ((const f32x4*)Wk)[i * 2 + 1];
            ((short8*)Wkb)[i] = pack8(a, b);
        }
    } else {
        const int n8 = (int)(((size_t)Nb * Lseq * Hdim) / 8);
        for (int i = (bid - 384) * 256 + tid; i < n8; i += 4096 * 256) {
            f32x4 a = ((const f32x4*)keys)[i * 2];
            f32x4 b = ((const f32x4*)keys)[i * 2 + 1];
            ((short8*)keysb)[i] = pack8(a, b);
        }
    }
}

// ============ 256x256 4-phase bf16 fused scores GEMM ============
// 2 phases per K-tile (32-MFMA clusters) — halved barrier count vs the 8-phase
// R8 version (which profiled LDS/sync-bound: MfmaUtil 39%, phase ~1270cyc vs
// ~155cyc MFMA). Staging ledger: tile t+2's {Aq0,Aq2,B q0-3} issued Ph2(t),
// {Aq1,Aq3} issued Ph1(t+1); steady outstanding at Ph2 wait = 14 -> vmcnt(6)
// retires exactly tile t+1's 8. Region lifetimes barrier-verified.
__global__ __launch_bounds__(512, 2) void fused_scores_bf16_4ph(
    const short* __restrict__ keysb, const short* __restrict__ Wkb,
    const float* __restrict__ qbuf, const float* __restrict__ vvec,
    float* __restrict__ Spart) {
    __shared__ __align__(16) short lds[65536];  // per dbuf (64KiB): A @0, B @32768 bytes

    const int tid = threadIdx.x, lane = tid & 63, wid = tid >> 6;
    const int wrow = wid >> 2, wcol = wid & 3;

    // XCD-chunked bijective grid mapping (nwg=1024, 8 XCDs x 128), a-block fastest
    const int bid = blockIdx.x;
    const int work = (bid & 7) * 128 + (bid >> 3);
    const int mblk = work >> 2, ablk = work & 3;
    const int m0 = mblk * 256, a0 = ablk * 256;

    // ---- staging: quarter = 64 rows x 64 cols; thread t -> row t>>3, granule t&7
    const int trow = tid >> 3;
    const int tswz = ((tid & 7) ^ (trow & 7)) * 8;  // pre-swizzled source granule (shorts)
    const short* Asrc = keysb + (size_t)(m0 + trow) * Hdim + tswz;
    const short* Bsrc = Wkb  + (size_t)(a0 + trow) * Hdim + tswz;
    char* Adst = (char*)lds + tid * 16;
    char* Bdst = (char*)lds + 32768 + tid * 16;

#define STG_A(d, q, kt) gload_lds16(Asrc + (size_t)(q) * 64 * Hdim + (kt) * 64, Adst + (d) * 65536 + (q) * 8192)
#define STG_B(d, q, kt) gload_lds16(Bsrc + (size_t)(q) * 64 * Hdim + (kt) * 64, Bdst + (d) * 65536 + (q) * 8192)

    // ---- fragment read offsets (bytes); kk=1 is ^64 (bit-6 disjoint under swizzle) ----
    int aoffb[8], boffb[4];
#pragma unroll
    for (int mi = 0; mi < 8; mi++) {
        int R = wrow * 128 + mi * 16 + (lane & 15);
        aoffb[mi] = R * 128 + (((lane >> 4) * 16) ^ ((R & 7) << 4));
    }
#pragma unroll
    for (int ni = 0; ni < 4; ni++) {
        int R = wcol * 64 + ni * 16 + (lane & 15);
        boffb[ni] = 32768 + R * 128 + (((lane >> 4) * 16) ^ ((R & 7) << 4));
    }
    const char* ldsb = (const char*)lds;

    short8 af[4][2], bf[4][2];
    f32x4 acc[8][4];
#pragma unroll
    for (int mi = 0; mi < 8; mi++)
#pragma unroll
        for (int ni = 0; ni < 4; ni++) acc[mi][ni] = (f32x4)0.0f;

#define LOAD_A4(d, mb) do { _Pragma("unroll") for (int m2 = 0; m2 < 4; m2++) { \
        af[m2][0] = *(const short8*)(ldsb + (d) * 65536 + aoffb[(mb) + m2]); \
        af[m2][1] = *(const short8*)(ldsb + (d) * 65536 + (aoffb[(mb) + m2] ^ 64)); } } while (0)
#define LOAD_B1(d, ni) do { \
        bf[ni][0] = *(const short8*)(ldsb + (d) * 65536 + boffb[ni]); \
        bf[ni][1] = *(const short8*)(ldsb + (d) * 65536 + (boffb[ni] ^ 64)); } while (0)
#define MFMA_Q(mb, nb) do { _Pragma("unroll") for (int m2 = 0; m2 < 4; m2++) \
        _Pragma("unroll") for (int n2 = 0; n2 < 2; n2++) { \
            acc[(mb) + m2][(nb) + n2] = __builtin_amdgcn_mfma_f32_16x16x32_bf16(af[m2][0], bf[(nb) + n2][0], acc[(mb) + m2][(nb) + n2], 0, 0, 0); \
            acc[(mb) + m2][(nb) + n2] = __builtin_amdgcn_mfma_f32_16x16x32_bf16(af[m2][1], bf[(nb) + n2][1], acc[(mb) + m2][(nb) + n2], 0, 0, 0); } } while (0)

#define BAR() __builtin_amdgcn_s_barrier()
#define WAITL() asm volatile("s_waitcnt lgkmcnt(0)" ::: "memory")
#define WAITV6() asm volatile("s_waitcnt vmcnt(6)" ::: "memory")
#define WAITV0() asm volatile("s_waitcnt vmcnt(0)" ::: "memory")
#define PRIO1() __builtin_amdgcn_s_setprio(1)
#define PRIO0() __builtin_amdgcn_s_setprio(0)

    // ---- prologue: tile 0 complete (8), tile 1's {Aq0,Aq2,B q0-3} (6) ----
    STG_A(0, 0, 0); STG_A(0, 1, 0); STG_A(0, 2, 0); STG_A(0, 3, 0);
    STG_B(0, 0, 0); STG_B(0, 1, 0); STG_B(0, 2, 0); STG_B(0, 3, 0);
    STG_A(1, 0, 1); STG_A(1, 2, 1);
    STG_B(1, 0, 1); STG_B(1, 1, 1); STG_B(1, 2, 1); STG_B(1, 3, 1);
    WAITV6();   // tile 0's 8 landed; tile 1's 6 in flight
    BAR();

#pragma unroll 1
    for (int t = 0; t < 16; ++t) {
        const int d = t & 1, od = d ^ 1;
        // ---- Ph1: full K-tile reads for mi0-3 + all B; MFMA (mi0-3 x ni0-3) ----
        LOAD_A4(d, 0);
        LOAD_B1(d, 0); LOAD_B1(d, 1); LOAD_B1(d, 2); LOAD_B1(d, 3);
        if (t + 1 < 16) { STG_A(od, 1, t + 1); STG_A(od, 3, t + 1); }  // tile t+1 last 2
        BAR(); WAITL();
        PRIO1(); MFMA_Q(0, 0); MFMA_Q(0, 2); PRIO0();
        BAR();
        // ---- Ph2: reads mi4-7; stage tile t+2's 6; counted vmcnt; MFMA (mi4-7 x ni0-3) ----
        LOAD_A4(d, 4);
        if (t + 2 < 16) {
            STG_A(d, 0, t + 2); STG_A(d, 2, t + 2);
            STG_B(d, 0, t + 2); STG_B(d, 1, t + 2); STG_B(d, 2, t + 2); STG_B(d, 3, t + 2);
        }
        if (t < 14) { WAITV6(); } else if (t == 14) { WAITV0(); }
        BAR(); WAITL();
        PRIO1(); MFMA_Q(4, 0); MFMA_Q(4, 2); PRIO0();
        BAR();
    }
#undef STG_A
#undef STG_B
#undef LOAD_A4
#undef LOAD_B1
#undef MFMA_Q

    // ---- epilogue: tanh(k + q[n,a]) * v[a], 16-col shuffle reduce, partial store ----
    const int n = m0 >> 11;
    float qv[4], vv[4];
#pragma unroll
    for (int ni = 0; ni < 4; ni++) {
        int acol = a0 + wcol * 64 + ni * 16 + (lane & 15);
        qv[ni] = qbuf[n * Adim + acol];
        vv[ni] = vvec[acol];
    }
#pragma unroll
    for (int mi = 0; mi < 8; mi++) {
#pragma unroll
        for (int r = 0; r < 4; r++) {
            float s = 0.f;
#pragma unroll
            for (int ni = 0; ni < 4; ni++) {
                float x = acc[mi][ni][r] + qv[ni];
                s += fast_tanh(x) * vv[ni];
            }
            s += __shfl_xor(s, 1); s += __shfl_xor(s, 2);
            s += __shfl_xor(s, 4); s += __shfl_xor(s, 8);
            if ((lane & 15) == 0) {
                int rglob = m0 + wrow * 128 + mi * 16 + (lane >> 4) * 4 + r;
                // 16 slices: (ablk, wcol) -> unique writer per element, no race
                Spart[(size_t)(ablk * 4 + wcol) * 65536 + rglob] = s;
            }
        }
    }
}

// ------------- softmax over L per n: sums 16 partial slices, writes weights -------------
__global__ __launch_bounds__(256) void softmax_part_kernel(const float* __restrict__ Spart,
                                                           float* __restrict__ S) {
    const int n = blockIdx.x, tid = threadIdx.x;
    const size_t base = (size_t)n * Lseq;
    __shared__ float red[4];
    const int w = tid >> 6, lane = tid & 63;
    float vals[8]; float m = -3e38f;
#pragma unroll
    for (int j = 0; j < 8; j++) {
        size_t idx = base + tid + j * 256;
        float s = 0.f;
#pragma unroll
        for (int p = 0; p < 16; p++) s += Spart[(size_t)p * 65536 + idx];
        vals[j] = s;
        m = fmaxf(m, vals[j]);
    }
#pragma unroll
    for (int s = 1; s < 64; s <<= 1) m = fmaxf(m, __shfl_xor(m, s));
    if (lane == 0) red[w] = m;
    __syncthreads();
    m = fmaxf(fmaxf(red[0], red[1]), fmaxf(red[2], red[3]));
    __syncthreads();
    float sum = 0.f;
#pragma unroll
    for (int j = 0; j < 8; j++) { vals[j] = __expf(vals[j] - m); sum += vals[j]; }
#pragma unroll
    for (int s = 1; s < 64; s <<= 1) sum += __shfl_xor(sum, s);
    if (lane == 0) red[w] = sum;
    __syncthreads();
    sum = red[0] + red[1] + red[2] + red[3];
    float inv = 1.0f / sum;
#pragma unroll
    for (int j = 0; j < 8; j++) S[base + tid + j * 256] = vals[j] * inv;
}

// -------- context partials: Cpart[ls][n*1024+h] over 128-l chunks, short4 loads --------
__global__ __launch_bounds__(256) void context_part_kernel(const short* __restrict__ keysb,
                                                           const float* __restrict__ S,
                                                           float* __restrict__ Cpart) {
    const int h0 = threadIdx.x * 4;                 // 4 h per thread, 1024 h per block
    const int ls = blockIdx.x, n = blockIdx.y;      // 16 chunks x 128 l
    const short* kb = keysb + ((size_t)n * Lseq + ls * 128) * Hdim + h0;
    const float* w = S + (size_t)n * Lseq + ls * 128;
    float a0 = 0.f, a1 = 0.f, a2 = 0.f, a3 = 0.f;
#pragma unroll 4
    for (int l = 0; l < 128; l++) {
        short4v u = *(const short4v*)(kb + (size_t)l * Hdim);
        float wl = w[l];
        a0 += wl * bf2f(u[0]); a1 += wl * bf2f(u[1]);
        a2 += wl * bf2f(u[2]); a3 += wl * bf2f(u[3]);
    }
    f32x4 r; r[0] = a0; r[1] = a1; r[2] = a2; r[3] = a3;
    *(f32x4*)(Cpart + (size_t)ls * (Nb * Hdim) + (size_t)n * Hdim + h0) = r;
}

// -------- context reduce: ctx[idx] = sum_{ls<16} Cpart[ls][idx] --------
__global__ __launch_bounds__(256) void context_reduce_kernel(const float* __restrict__ Cpart,
                                                             float* __restrict__ ctx) {
    const int idx = blockIdx.x * 256 + threadIdx.x;  // 0..32767
    float s = 0.f;
#pragma unroll
    for (int p = 0; p < 16; p++) s += Cpart[(size_t)p * (Nb * Hdim) + idx];
    ctx[idx] = s;
}

// ------------- f32 reg-staged fallback (proven R1 kernel + XCD grouping) -------------
__global__ __launch_bounds__(256, 2) void fused_scores_kernel(
    const float* __restrict__ keys, const float* __restrict__ Wk,
    const float* __restrict__ qbuf, const float* __restrict__ vvec,
    float* __restrict__ S) {
    __shared__ __align__(16) unsigned char lds[32768];

    const int tid = threadIdx.x;
    const int bid = blockIdx.x;
    const int mblk = ((bid >> 6) << 3) | (bid & 7);
    const int ablk = (bid >> 3) & 7;
    const int m0 = mblk * 128, a0 = ablk * 128;
    const int lane = tid & 63, wid = tid >> 6;
    const int wr = (wid >> 1) * 64, wc = (wid & 1) * 64;

    const float* ag[4]; const float* bg[4]; int offA[4], offB[4];
#pragma unroll
    for (int c = 0; c < 4; c++) {
        int p = tid + c * 256;
        int row = p >> 3, pp = p & 7;
        ag[c] = keys + (size_t)(m0 + row) * Hdim + pp * 8;
        bg[c] = Wk + (size_t)(a0 + row) * Hdim + pp * 8;
        int sw = row * 128 + ((pp * 16) ^ ((row & 7) << 4));
        offA[c] = sw; offB[c] = 16384 + sw;
    }

    int abase[4], amask[4], bbase[4], bmask[4];
    const int kb0 = (lane >> 4) * 16;
#pragma unroll
    for (int i = 0; i < 4; i++) {
        int rowa = wr + i * 16 + (lane & 15);
        abase[i] = rowa * 128; amask[i] = (rowa & 7) << 4;
        int rowb = wc + i * 16 + (lane & 15);
        bbase[i] = 16384 + rowb * 128; bmask[i] = (rowb & 7) << 4;
    }

    f32x4 la[4][2], lb[4][2];
#pragma unroll
    for (int c = 0; c < 4; c++) {
        la[c][0] = *(const f32x4*)(ag[c]);     la[c][1] = *(const f32x4*)(ag[c] + 4);
        lb[c][0] = *(const f32x4*)(bg[c]);     lb[c][1] = *(const f32x4*)(bg[c] + 4);
    }
    short8 sa[4], sb[4];
#pragma unroll
    for (int c = 0; c < 4; c++) { sa[c] = pack8(la[c][0], la[c][1]); sb[c] = pack8(lb[c][0], lb[c][1]); }

    f32x4 acc[4][4];
#pragma unroll
    for (int mi = 0; mi < 4; mi++)
#pragma unroll
        for (int ni = 0; ni < 4; ni++) acc[mi][ni] = (f32x4)0.0f;

    for (int t = 0; t < 16; t++) {
        __syncthreads();
#pragma unroll
        for (int c = 0; c < 4; c++) {
            *(short8*)(lds + offA[c]) = sa[c];
            *(short8*)(lds + offB[c]) = sb[c];
        }
        if (t < 15) {
            const int k0 = (t + 1) * 64;
#pragma unroll
            for (int c = 0; c < 4; c++) {
                la[c][0] = *(const f32x4*)(ag[c] + k0);     la[c][1] = *(const f32x4*)(ag[c] + k0 + 4);
                lb[c][0] = *(const f32x4*)(bg[c] + k0);     lb[c][1] = *(const f32x4*)(bg[c] + k0 + 4);
            }
        }
        __syncthreads();
#pragma unroll
        for (int kk = 0; kk < 2; kk++) {
            short8 af[4], bf[4];
#pragma unroll
            for (int i = 0; i < 4; i++)
                af[i] = *(const short8*)(lds + abase[i] + ((kk * 64 + kb0) ^ amask[i]));
#pragma unroll
            for (int i = 0; i < 4; i++)
                bf[i] = *(const short8*)(lds + bbase[i] + ((kk * 64 + kb0) ^ bmask[i]));
#pragma unroll
            for (int mi = 0; mi < 4; mi++)
#pragma unroll
                for (int ni = 0; ni < 4; ni++)
                    acc[mi][ni] = __builtin_amdgcn_mfma_f32_16x16x32_bf16(af[mi], bf[ni], acc[mi][ni], 0, 0, 0);
        }
        if (t < 15) {
#pragma unroll
            for (int c = 0; c < 4; c++) { sa[c] = pack8(la[c][0], la[c][1]); sb[c] = pack8(lb[c][0], lb[c][1]); }
        }
    }

    const int n = m0 >> 11;
    float qv[4], vv[4];
#pragma unroll
    for (int ni = 0; ni < 4; ni++) {
        int acol = a0 + wc + ni * 16 + (lane & 15);
        qv[ni] = qbuf[n * Adim + acol];
        vv[ni] = vvec[acol];
    }
#pragma unroll
    for (int mi = 0; mi < 4; mi++) {
#pragma unroll
        for (int r = 0; r < 4; r++) {
            float s = 0.f;
#pragma unroll
            for (int ni = 0; ni < 4; ni++) {
                float x = acc[mi][ni][r] + qv[ni];
                s += fast_tanh(x) * vv[ni];
            }
            s += __shfl_xor(s, 1); s += __shfl_xor(s, 2);
            s += __shfl_xor(s, 4); s += __shfl_xor(s, 8);
            if ((lane & 15) == 0) {
                int rglob = m0 + wr + mi * 16 + (lane >> 4) * 4 + r;
                atomicAdd(&S[rglob], s);
            }
        }
    }
}

// ---------------- softmax (in-place, fallback path) ----------------
__global__ __launch_bounds__(256) void softmax_kernel(float* __restrict__ S) {
    const int n = blockIdx.x, tid = threadIdx.x;
    float* row = S + (size_t)n * Lseq;
    __shared__ float red[4];
    const int w = tid >> 6, lane = tid & 63;
    float vals[8]; float m = -3e38f;
#pragma unroll
    for (int j = 0; j < 8; j++) { vals[j] = row[tid + j * 256]; m = fmaxf(m, vals[j]); }
#pragma unroll
    for (int s = 1; s < 64; s <<= 1) m = fmaxf(m, __shfl_xor(m, s));
    if (lane == 0) red[w] = m;
    __syncthreads();
    m = fmaxf(fmaxf(red[0], red[1]), fmaxf(red[2], red[3]));
    __syncthreads();
    float sum = 0.f;
#pragma unroll
    for (int j = 0; j < 8; j++) { vals[j] = __expf(vals[j] - m); sum += vals[j]; }
#pragma unroll
    for (int s = 1; s < 64; s <<= 1) sum += __shfl_xor(sum, s);
    if (lane == 0) red[w] = sum;
    __syncthreads();
    sum = red[0] + red[1] + red[2] + red[3];
    float inv = 1.0f / sum;
#pragma unroll
    for (int j = 0; j < 8; j++) row[tid + j * 256] = vals[j] * inv;
}

// ---------------- f32 context fallback ----------------
__global__ __launch_bounds__(256) void context_kernel(const float* __restrict__ keys,
                                                      const float* __restrict__ S,
                                                      float* __restrict__ ctx) {
    const int hc = blockIdx.x;
    const int ls = blockIdx.y;
    const int n = blockIdx.z;
    const int h = hc * 256 + threadIdx.x;
    const float* kb = keys + ((size_t)n * Lseq + ls * 256) * Hdim + h;
    const float* w = S + (size_t)n * Lseq + ls * 256;
    float acc = 0.f;
#pragma unroll 4
    for (int l = 0; l < 256; l++) acc += w[l] * kb[(size_t)l * Hdim];
    atomicAdd(&ctx[n * Hdim + h], acc);
}

extern "C" void kernel_launch(void* const* d_in, const int* in_sizes, int n_in,
                              void* d_out, int out_size, void* d_ws, size_t ws_size,
                              hipStream_t stream) {
    const float* query = (const float*)d_in[0];
    const float* keys  = (const float*)d_in[1];
    const float* Wq = (const float*)d_in[3];
    const float* Wk = (const float*)d_in[4];
    const float* v  = (const float*)d_in[5];

    float* out = (float*)d_out;
    float* ctx = out;                    // [32 x 1024] context region (holds q temporarily)
    float* S   = out + Nb * Hdim;        // [32 x 2048] attn-weights region

    const size_t keys_elems = (size_t)Nb * Lseq * Hdim;   // 33,554,432
    const size_t wk_elems = (size_t)Adim * Hdim;          // 1,048,576
    // ws layout: keysb | Wkb | Spart[16][65536] | Cpart[16][32768]
    const size_t spart_off_f = (keys_elems + wk_elems) / 2;        // float offset
    const size_t cpart_off_f = spart_off_f + 16 * 65536;
    const size_t need = (keys_elems + wk_elems) * 2 + (16 * 65536 + 16 * 32768) * 4;

    if (ws_size >= need) {
        short* keysb = (short*)d_ws;
        short* Wkb = keysb + keys_elems;
        float* Spart = (float*)d_ws + spart_off_f;
        float* Cpart = (float*)d_ws + cpart_off_f;
        // fused prep: q | cvt Wk | cvt keys in one launch
        prep_kernel<<<dim3(4480), dim3(256), 0, stream>>>(query, Wq, ctx, Wk, Wkb, keys, keysb);
        fused_scores_bf16_4ph<<<dim3((Nb * Lseq / 256) * (Adim / 256)), dim3(512), 0, stream>>>(
            keysb, Wkb, ctx, v, Spart);
        softmax_part_kernel<<<dim3(Nb), dim3(256), 0, stream>>>(Spart, S);
        context_part_kernel<<<dim3(16, 32), dim3(256), 0, stream>>>(keysb, S, Cpart);
        context_reduce_kernel<<<dim3(Nb * Hdim / 256), dim3(256), 0, stream>>>(Cpart, ctx);
    } else {
        q_kernel<<<dim3((Nb * Adim) / 256), dim3(256), 0, stream>>>(query, Wq, ctx);
        hipMemsetAsync(S, 0, (size_t)Nb * Lseq * sizeof(float), stream);
        fused_scores_kernel<<<dim3((Nb * Lseq / 128) * (Adim / 128)), dim3(256), 0, stream>>>(
            keys, Wk, ctx, v, S);
        softmax_kernel<<<dim3(Nb), dim3(256), 0, stream>>>(S);
        hipMemsetAsync(ctx, 0, (size_t)Nb * Hdim * sizeof(float), stream);
        context_kernel<<<dim3(4, 8, Nb), dim3(256), 0, stream>>>(keys, S, ctx);
    }
}

// Round 13
// 253.221 us; speedup vs baseline: 1.0260x; 1.0260x over previous
//
#include <hip/hip_runtime.h>
#include <hip/hip_bf16.h>

typedef __attribute__((ext_vector_type(8))) short short8;
typedef __attribute__((ext_vector_type(4))) short short4v;
typedef __attribute__((ext_vector_type(4))) float f32x4;

static constexpr int Nb = 32, Lseq = 2048, Hdim = 1024, Adim = 1024;
// M = Nb*Lseq = 65536 rows; GEMM: [M x A] = keys[M x H] * Wk^T[H x A]

__device__ __forceinline__ short8 pack8(f32x4 a, f32x4 b) {
    short8 r;
#pragma unroll
    for (int i = 0; i < 4; i++) { __bf16 h = (__bf16)a[i]; r[i] = __builtin_bit_cast(short, h); }
#pragma unroll
    for (int i = 0; i < 4; i++) { __bf16 h = (__bf16)b[i]; r[i + 4] = __builtin_bit_cast(short, h); }
    return r;
}

__device__ __forceinline__ float bf2f(short s) {
    return __builtin_bit_cast(float, (unsigned)(unsigned short)s << 16);
}

__device__ __forceinline__ float fast_tanh(float x) {
    float ex = __expf(2.0f * x);
    return 1.0f - 2.0f * __builtin_amdgcn_rcpf(ex + 1.0f);
}

__device__ __forceinline__ void gload_lds16(const void* g, void* l) {
    __builtin_amdgcn_global_load_lds(
        (const __attribute__((address_space(1))) unsigned int*)g,
        (__attribute__((address_space(3))) unsigned int*)l, 16, 0, 0);
}

// ---------------- q = query @ Wq^T : [32 x 1024] (fallback) ----------------
__global__ __launch_bounds__(256) void q_kernel(const float* __restrict__ query,
                                                const float* __restrict__ Wq,
                                                float* __restrict__ qout) {
    int idx = blockIdx.x * 256 + threadIdx.x;
    int n = idx >> 10, a = idx & 1023;
    const f32x4* qr = (const f32x4*)(query + (size_t)n * Hdim);
    const f32x4* wr = (const f32x4*)(Wq + (size_t)a * Hdim);
    float acc = 0.f;
#pragma unroll 8
    for (int i = 0; i < Hdim / 4; i++) {
        f32x4 x = qr[i], y = wr[i];
        acc += x[0] * y[0]; acc += x[1] * y[1]; acc += x[2] * y[2]; acc += x[3] * y[3];
    }
    qout[idx] = acc;
}

// ---------------- fused prep: q (128 blk) | cvt Wk (256 blk) | cvt keys (4096 blk) ----------------
__global__ __launch_bounds__(256) void prep_kernel(const float* __restrict__ query,
                                                   const float* __restrict__ Wq,
                                                   float* __restrict__ qout,
                                                   const float* __restrict__ Wk,
                                                   short* __restrict__ Wkb,
                                                   const float* __restrict__ keys,
                                                   short* __restrict__ keysb) {
    const int bid = blockIdx.x, tid = threadIdx.x;
    if (bid < 128) {
        int idx = bid * 256 + tid;
        int n = idx >> 10, a = idx & 1023;
        const f32x4* qr = (const f32x4*)(query + (size_t)n * Hdim);
        const f32x4* wr = (const f32x4*)(Wq + (size_t)a * Hdim);
        float acc = 0.f;
#pragma unroll 8
        for (int i = 0; i < Hdim / 4; i++) {
            f32x4 x = qr[i], y = wr[i];
            acc += x[0] * y[0]; acc += x[1] * y[1]; acc += x[2] * y[2]; acc += x[3] * y[3];
        }
        qout[idx] = acc;
    } else if (bid < 384) {
        const int n8 = (Adim * Hdim) / 8;
        for (int i = (bid - 128) * 256 + tid; i < n8; i += 256 * 256) {
            f32x4 a = ((const f32x4*)Wk)[i * 2];
            f32x4 b = ((const f32x4*)Wk)[i * 2 + 1];
            ((short8*)Wkb)[i] = pack8(a, b);
        }
    } else {
        const int n8 = (int)(((size_t)Nb * Lseq * Hdim) / 8);
        for (int i = (bid - 384) * 256 + tid; i < n8; i += 4096 * 256) {
            f32x4 a = ((const f32x4*)keys)[i * 2];
            f32x4 b = ((const f32x4*)keys)[i * 2 + 1];
            ((short8*)keysb)[i] = pack8(a, b);
        }
    }
}

// ============ 256x256 8-phase bf16 fused scores GEMM (R8, PROVEN: 151 us) ============
// BK=64, 2 K-tiles/iter, 8 waves (2Mx4N), 2 dbuf x {A 256x64, B 256x64} = 128 KiB,
// quarter-tile staging (2 gload_lds16/phase), counted vmcnt(6) at phases 4/8 only,
// 3-bit XOR swizzle on 128B rows (bank-conflict-free, measured 0).
// Per-phase lgkmcnt(0) asm is BOTH the wait and the compiler memory fence (keeps
// all LDS/DMA ops pinned in their phase — removing it was the R10-R12 failure).
// Epilogue: NON-ATOMIC partial store to Spart[ablk*4 + wcol][m] (16 slices, unique writer).
__global__ __launch_bounds__(512, 2) void fused_scores_bf16_8ph(
    const short* __restrict__ keysb, const short* __restrict__ Wkb,
    const float* __restrict__ qbuf, const float* __restrict__ vvec,
    float* __restrict__ Spart) {
    __shared__ __align__(16) short lds[65536];  // per dbuf (64KiB): A @0, B @32768 bytes

    const int tid = threadIdx.x, lane = tid & 63, wid = tid >> 6;
    const int wrow = wid >> 2, wcol = wid & 3;

    // XCD-chunked bijective grid mapping (nwg=1024, 8 XCDs x 128), a-block fastest
    const int bid = blockIdx.x;
    const int work = (bid & 7) * 128 + (bid >> 3);
    const int mblk = work >> 2, ablk = work & 3;
    const int m0 = mblk * 256, a0 = ablk * 256;

    // ---- staging: quarter = 64 rows x 64 cols; thread t -> row t>>3, granule t&7
    const int trow = tid >> 3;
    const int tswz = ((tid & 7) ^ (trow & 7)) * 8;  // pre-swizzled source granule (shorts)
    const short* Asrc = keysb + (size_t)(m0 + trow) * Hdim + tswz;
    const short* Bsrc = Wkb  + (size_t)(a0 + trow) * Hdim + tswz;
    char* Adst = (char*)lds + tid * 16;
    char* Bdst = (char*)lds + 32768 + tid * 16;

#define STG_A(d, q, kt) gload_lds16(Asrc + (size_t)(q) * 64 * Hdim + (kt) * 64, Adst + (d) * 65536 + (q) * 8192)
#define STG_B(d, q, kt) gload_lds16(Bsrc + (size_t)(q) * 64 * Hdim + (kt) * 64, Bdst + (d) * 65536 + (q) * 8192)

    // ---- fragment read offsets (bytes); kk=1 is ^64 (bit-6 disjoint under swizzle) ----
    int aoffb[8], boffb[4];
#pragma unroll
    for (int mi = 0; mi < 8; mi++) {
        int R = wrow * 128 + mi * 16 + (lane & 15);
        aoffb[mi] = R * 128 + (((lane >> 4) * 16) ^ ((R & 7) << 4));
    }
#pragma unroll
    for (int ni = 0; ni < 4; ni++) {
        int R = wcol * 64 + ni * 16 + (lane & 15);
        boffb[ni] = 32768 + R * 128 + (((lane >> 4) * 16) ^ ((R & 7) << 4));
    }
    const char* ldsb = (const char*)lds;

    short8 af[4][2], bf[4][2];
    f32x4 acc[8][4];
#pragma unroll
    for (int mi = 0; mi < 8; mi++)
#pragma unroll
        for (int ni = 0; ni < 4; ni++) acc[mi][ni] = (f32x4)0.0f;

#define LOAD_A4(d, mb) do { _Pragma("unroll") for (int m2 = 0; m2 < 4; m2++) { \
        af[m2][0] = *(const short8*)(ldsb + (d) * 65536 + aoffb[(mb) + m2]); \
        af[m2][1] = *(const short8*)(ldsb + (d) * 65536 + (aoffb[(mb) + m2] ^ 64)); } } while (0)
#define LOAD_B1(d, ni) do { \
        bf[ni][0] = *(const short8*)(ldsb + (d) * 65536 + boffb[ni]); \
        bf[ni][1] = *(const short8*)(ldsb + (d) * 65536 + (boffb[ni] ^ 64)); } while (0)
#define MFMA_Q(mb, nb) do { _Pragma("unroll") for (int m2 = 0; m2 < 4; m2++) \
        _Pragma("unroll") for (int n2 = 0; n2 < 2; n2++) { \
            acc[(mb) + m2][(nb) + n2] = __builtin_amdgcn_mfma_f32_16x16x32_bf16(af[m2][0], bf[(nb) + n2][0], acc[(mb) + m2][(nb) + n2], 0, 0, 0); \
            acc[(mb) + m2][(nb) + n2] = __builtin_amdgcn_mfma_f32_16x16x32_bf16(af[m2][1], bf[(nb) + n2][1], acc[(mb) + m2][(nb) + n2], 0, 0, 0); } } while (0)

#define BAR() __builtin_amdgcn_s_barrier()
#define WAITL() asm volatile("s_waitcnt lgkmcnt(0)" ::: "memory")
#define WAITV6() asm volatile("s_waitcnt vmcnt(6)" ::: "memory")
#define PRIO1() __builtin_amdgcn_s_setprio(1)
#define PRIO0() __builtin_amdgcn_s_setprio(0)

    // ---- prologue: tile 0 complete (8 quarters), tile 1 first 6 quarters ----
    STG_A(0, 0, 0); STG_A(0, 2, 0);
    STG_B(0, 0, 0); STG_B(0, 1, 0);
    STG_B(0, 2, 0); STG_B(0, 3, 0);
    STG_A(0, 1, 0); STG_A(0, 3, 0);
    STG_A(1, 0, 1); STG_A(1, 2, 1);
    STG_B(1, 0, 1); STG_B(1, 1, 1);
    STG_B(1, 2, 1); STG_B(1, 3, 1);
    WAITV6();   // tile 0 landed; tile 1's 6 stay in flight
    BAR();

#pragma unroll 1
    for (int i = 0; i < 8; ++i) {
        const int k1 = (2 * i + 1) & 15, k2 = (2 * i + 2) & 15, k3 = (2 * i + 3) & 15;
        // ---- phase 1: tile 2i quadrant (mi0-3 x ni0-1) ----
        LOAD_A4(0, 0); LOAD_B1(0, 0); LOAD_B1(0, 1);
        STG_A(1, 1, k1); STG_A(1, 3, k1);
        BAR(); WAITL(); PRIO1(); MFMA_Q(0, 0); PRIO0(); BAR();
        // ---- phase 2: (mi0-3 x ni2-3) ----
        LOAD_B1(0, 2); LOAD_B1(0, 3);
        STG_A(0, 0, k2); STG_A(0, 2, k2);
        BAR(); WAITL(); PRIO1(); MFMA_Q(0, 2); PRIO0(); BAR();
        // ---- phase 3: (mi4-7 x ni2-3) ----
        LOAD_A4(0, 4);
        STG_B(0, 0, k2); STG_B(0, 1, k2);
        BAR(); WAITL(); PRIO1(); MFMA_Q(4, 2); PRIO0(); BAR();
        // ---- phase 4: (mi4-7 x ni0-1), counted vmcnt ----
        STG_B(0, 2, k2); STG_B(0, 3, k2);
        WAITV6();   // tile 2i+1 fully landed
        BAR(); PRIO1(); MFMA_Q(4, 0); PRIO0(); BAR();
        // ---- phase 5: tile 2i+1 quadrant (mi0-3 x ni0-1) ----
        LOAD_A4(1, 0); LOAD_B1(1, 0); LOAD_B1(1, 1);
        STG_A(0, 1, k2); STG_A(0, 3, k2);
        BAR(); WAITL(); PRIO1(); MFMA_Q(0, 0); PRIO0(); BAR();
        // ---- phase 6: (mi0-3 x ni2-3) ----
        LOAD_B1(1, 2); LOAD_B1(1, 3);
        STG_A(1, 0, k3); STG_A(1, 2, k3);
        BAR(); WAITL(); PRIO1(); MFMA_Q(0, 2); PRIO0(); BAR();
        // ---- phase 7: (mi4-7 x ni2-3) ----
        LOAD_A4(1, 4);
        STG_B(1, 0, k3); STG_B(1, 1, k3);
        BAR(); WAITL(); PRIO1(); MFMA_Q(4, 2); PRIO0(); BAR();
        // ---- phase 8: (mi4-7 x ni0-1), counted vmcnt ----
        STG_B(1, 2, k3); STG_B(1, 3, k3);
        WAITV6();   // tile 2i+2 fully landed
        BAR(); PRIO1(); MFMA_Q(4, 0); PRIO0(); BAR();
    }
#undef STG_A
#undef STG_B
#undef LOAD_A4
#undef LOAD_B1
#undef MFMA_Q

    // ---- epilogue: tanh(k + q[n,a]) * v[a], 16-col shuffle reduce, partial store ----
    const int n = m0 >> 11;
    float qv[4], vv[4];
#pragma unroll
    for (int ni = 0; ni < 4; ni++) {
        int acol = a0 + wcol * 64 + ni * 16 + (lane & 15);
        qv[ni] = qbuf[n * Adim + acol];
        vv[ni] = vvec[acol];
    }
#pragma unroll
    for (int mi = 0; mi < 8; mi++) {
#pragma unroll
        for (int r = 0; r < 4; r++) {
            float s = 0.f;
#pragma unroll
            for (int ni = 0; ni < 4; ni++) {
                float x = acc[mi][ni][r] + qv[ni];
                s += fast_tanh(x) * vv[ni];
            }
            s += __shfl_xor(s, 1); s += __shfl_xor(s, 2);
            s += __shfl_xor(s, 4); s += __shfl_xor(s, 8);
            if ((lane & 15) == 0) {
                int rglob = m0 + wrow * 128 + mi * 16 + (lane >> 4) * 4 + r;
                // 16 slices: (ablk, wcol) -> unique writer per element, no race
                Spart[(size_t)(ablk * 4 + wcol) * 65536 + rglob] = s;
            }
        }
    }
}

// ------------- softmax over L per n: sums 16 partial slices, writes weights -------------
__global__ __launch_bounds__(256) void softmax_part_kernel(const float* __restrict__ Spart,
                                                           float* __restrict__ S) {
    const int n = blockIdx.x, tid = threadIdx.x;
    const size_t base = (size_t)n * Lseq;
    __shared__ float red[4];
    const int w = tid >> 6, lane = tid & 63;
    float vals[8]; float m = -3e38f;
#pragma unroll
    for (int j = 0; j < 8; j++) {
        size_t idx = base + tid + j * 256;
        float s = 0.f;
#pragma unroll
        for (int p = 0; p < 16; p++) s += Spart[(size_t)p * 65536 + idx];
        vals[j] = s;
        m = fmaxf(m, vals[j]);
    }
#pragma unroll
    for (int s = 1; s < 64; s <<= 1) m = fmaxf(m, __shfl_xor(m, s));
    if (lane == 0) red[w] = m;
    __syncthreads();
    m = fmaxf(fmaxf(red[0], red[1]), fmaxf(red[2], red[3]));
    __syncthreads();
    float sum = 0.f;
#pragma unroll
    for (int j = 0; j < 8; j++) { vals[j] = __expf(vals[j] - m); sum += vals[j]; }
#pragma unroll
    for (int s = 1; s < 64; s <<= 1) sum += __shfl_xor(sum, s);
    if (lane == 0) red[w] = sum;
    __syncthreads();
    sum = red[0] + red[1] + red[2] + red[3];
    float inv = 1.0f / sum;
#pragma unroll
    for (int j = 0; j < 8; j++) S[base + tid + j * 256] = vals[j] * inv;
}

// -------- context partials: Cpart[ls][n*1024+h] over 128-l chunks, short4 loads --------
__global__ __launch_bounds__(256) void context_part_kernel(const short* __restrict__ keysb,
                                                           const float* __restrict__ S,
                                                           float* __restrict__ Cpart) {
    const int h0 = threadIdx.x * 4;                 // 4 h per thread, 1024 h per block
    const int ls = blockIdx.x, n = blockIdx.y;      // 16 chunks x 128 l
    const short* kb = keysb + ((size_t)n * Lseq + ls * 128) * Hdim + h0;
    const float* w = S + (size_t)n * Lseq + ls * 128;
    float a0 = 0.f, a1 = 0.f, a2 = 0.f, a3 = 0.f;
#pragma unroll 4
    for (int l = 0; l < 128; l++) {
        short4v u = *(const short4v*)(kb + (size_t)l * Hdim);
        float wl = w[l];
        a0 += wl * bf2f(u[0]); a1 += wl * bf2f(u[1]);
        a2 += wl * bf2f(u[2]); a3 += wl * bf2f(u[3]);
    }
    f32x4 r; r[0] = a0; r[1] = a1; r[2] = a2; r[3] = a3;
    *(f32x4*)(Cpart + (size_t)ls * (Nb * Hdim) + (size_t)n * Hdim + h0) = r;
}

// -------- context reduce: ctx[idx] = sum_{ls<16} Cpart[ls][idx] --------
__global__ __launch_bounds__(256) void context_reduce_kernel(const float* __restrict__ Cpart,
                                                             float* __restrict__ ctx) {
    const int idx = blockIdx.x * 256 + threadIdx.x;  // 0..32767
    float s = 0.f;
#pragma unroll
    for (int p = 0; p < 16; p++) s += Cpart[(size_t)p * (Nb * Hdim) + idx];
    ctx[idx] = s;
}

// ------------- f32 reg-staged fallback (proven R1 kernel + XCD grouping) -------------
__global__ __launch_bounds__(256, 2) void fused_scores_kernel(
    const float* __restrict__ keys, const float* __restrict__ Wk,
    const float* __restrict__ qbuf, const float* __restrict__ vvec,
    float* __restrict__ S) {
    __shared__ __align__(16) unsigned char lds[32768];

    const int tid = threadIdx.x;
    const int bid = blockIdx.x;
    const int mblk = ((bid >> 6) << 3) | (bid & 7);
    const int ablk = (bid >> 3) & 7;
    const int m0 = mblk * 128, a0 = ablk * 128;
    const int lane = tid & 63, wid = tid >> 6;
    const int wr = (wid >> 1) * 64, wc = (wid & 1) * 64;

    const float* ag[4]; const float* bg[4]; int offA[4], offB[4];
#pragma unroll
    for (int c = 0; c < 4; c++) {
        int p = tid + c * 256;
        int row = p >> 3, pp = p & 7;
        ag[c] = keys + (size_t)(m0 + row) * Hdim + pp * 8;
        bg[c] = Wk + (size_t)(a0 + row) * Hdim + pp * 8;
        int sw = row * 128 + ((pp * 16) ^ ((row & 7) << 4));
        offA[c] = sw; offB[c] = 16384 + sw;
    }

    int abase[4], amask[4], bbase[4], bmask[4];
    const int kb0 = (lane >> 4) * 16;
#pragma unroll
    for (int i = 0; i < 4; i++) {
        int rowa = wr + i * 16 + (lane & 15);
        abase[i] = rowa * 128; amask[i] = (rowa & 7) << 4;
        int rowb = wc + i * 16 + (lane & 15);
        bbase[i] = 16384 + rowb * 128; bmask[i] = (rowb & 7) << 4;
    }

    f32x4 la[4][2], lb[4][2];
#pragma unroll
    for (int c = 0; c < 4; c++) {
        la[c][0] = *(const f32x4*)(ag[c]);     la[c][1] = *(const f32x4*)(ag[c] + 4);
        lb[c][0] = *(const f32x4*)(bg[c]);     lb[c][1] = *(const f32x4*)(bg[c] + 4);
    }
    short8 sa[4], sb[4];
#pragma unroll
    for (int c = 0; c < 4; c++) { sa[c] = pack8(la[c][0], la[c][1]); sb[c] = pack8(lb[c][0], lb[c][1]); }

    f32x4 acc[4][4];
#pragma unroll
    for (int mi = 0; mi < 4; mi++)
#pragma unroll
        for (int ni = 0; ni < 4; ni++) acc[mi][ni] = (f32x4)0.0f;

    for (int t = 0; t < 16; t++) {
        __syncthreads();
#pragma unroll
        for (int c = 0; c < 4; c++) {
            *(short8*)(lds + offA[c]) = sa[c];
            *(short8*)(lds + offB[c]) = sb[c];
        }
        if (t < 15) {
            const int k0 = (t + 1) * 64;
#pragma unroll
            for (int c = 0; c < 4; c++) {
                la[c][0] = *(const f32x4*)(ag[c] + k0);     la[c][1] = *(const f32x4*)(ag[c] + k0 + 4);
                lb[c][0] = *(const f32x4*)(bg[c] + k0);     lb[c][1] = *(const f32x4*)(bg[c] + k0 + 4);
            }
        }
        __syncthreads();
#pragma unroll
        for (int kk = 0; kk < 2; kk++) {
            short8 af[4], bf[4];
#pragma unroll
            for (int i = 0; i < 4; i++)
                af[i] = *(const short8*)(lds + abase[i] + ((kk * 64 + kb0) ^ amask[i]));
#pragma unroll
            for (int i = 0; i < 4; i++)
                bf[i] = *(const short8*)(lds + bbase[i] + ((kk * 64 + kb0) ^ bmask[i]));
#pragma unroll
            for (int mi = 0; mi < 4; mi++)
#pragma unroll
                for (int ni = 0; ni < 4; ni++)
                    acc[mi][ni] = __builtin_amdgcn_mfma_f32_16x16x32_bf16(af[mi], bf[ni], acc[mi][ni], 0, 0, 0);
        }
        if (t < 15) {
#pragma unroll
            for (int c = 0; c < 4; c++) { sa[c] = pack8(la[c][0], la[c][1]); sb[c] = pack8(lb[c][0], lb[c][1]); }
        }
    }

    const int n = m0 >> 11;
    float qv[4], vv[4];
#pragma unroll
    for (int ni = 0; ni < 4; ni++) {
        int acol = a0 + wc + ni * 16 + (lane & 15);
        qv[ni] = qbuf[n * Adim + acol];
        vv[ni] = vvec[acol];
    }
#pragma unroll
    for (int mi = 0; mi < 4; mi++) {
#pragma unroll
        for (int r = 0; r < 4; r++) {
            float s = 0.f;
#pragma unroll
            for (int ni = 0; ni < 4; ni++) {
                float x = acc[mi][ni][r] + qv[ni];
                s += fast_tanh(x) * vv[ni];
            }
            s += __shfl_xor(s, 1); s += __shfl_xor(s, 2);
            s += __shfl_xor(s, 4); s += __shfl_xor(s, 8);
            if ((lane & 15) == 0) {
                int rglob = m0 + wr + mi * 16 + (lane >> 4) * 4 + r;
                atomicAdd(&S[rglob], s);
            }
        }
    }
}

// ---------------- softmax (in-place, fallback path) ----------------
__global__ __launch_bounds__(256) void softmax_kernel(float* __restrict__ S) {
    const int n = blockIdx.x, tid = threadIdx.x;
    float* row = S + (size_t)n * Lseq;
    __shared__ float red[4];
    const int w = tid >> 6, lane = tid & 63;
    float vals[8]; float m = -3e38f;
#pragma unroll
    for (int j = 0; j < 8; j++) { vals[j] = row[tid + j * 256]; m = fmaxf(m, vals[j]); }
#pragma unroll
    for (int s = 1; s < 64; s <<= 1) m = fmaxf(m, __shfl_xor(m, s));
    if (lane == 0) red[w] = m;
    __syncthreads();
    m = fmaxf(fmaxf(red[0], red[1]), fmaxf(red[2], red[3]));
    __syncthreads();
    float sum = 0.f;
#pragma unroll
    for (int j = 0; j < 8; j++) { vals[j] = __expf(vals[j] - m); sum += vals[j]; }
#pragma unroll
    for (int s = 1; s < 64; s <<= 1) sum += __shfl_xor(sum, s);
    if (lane == 0) red[w] = sum;
    __syncthreads();
    sum = red[0] + red[1] + red[2] + red[3];
    float inv = 1.0f / sum;
#pragma unroll
    for (int j = 0; j < 8; j++) row[tid + j * 256] = vals[j] * inv;
}

// ---------------- f32 context fallback ----------------
__global__ __launch_bounds__(256) void context_kernel(const float* __restrict__ keys,
                                                      const float* __restrict__ S,
                                                      float* __restrict__ ctx) {
    const int hc = blockIdx.x;
    const int ls = blockIdx.y;
    const int n = blockIdx.z;
    const int h = hc * 256 + threadIdx.x;
    const float* kb = keys + ((size_t)n * Lseq + ls * 256) * Hdim + h;
    const float* w = S + (size_t)n * Lseq + ls * 256;
    float acc = 0.f;
#pragma unroll 4
    for (int l = 0; l < 256; l++) acc += w[l] * kb[(size_t)l * Hdim];
    atomicAdd(&ctx[n * Hdim + h], acc);
}

extern "C" void kernel_launch(void* const* d_in, const int* in_sizes, int n_in,
                              void* d_out, int out_size, void* d_ws, size_t ws_size,
                              hipStream_t stream) {
    const float* query = (const float*)d_in[0];
    const float* keys  = (const float*)d_in[1];
    const float* Wq = (const float*)d_in[3];
    const float* Wk = (const float*)d_in[4];
    const float* v  = (const float*)d_in[5];

    float* out = (float*)d_out;
    float* ctx = out;                    // [32 x 1024] context region (holds q temporarily)
    float* S   = out + Nb * Hdim;        // [32 x 2048] attn-weights region

    const size_t keys_elems = (size_t)Nb * Lseq * Hdim;   // 33,554,432
    const size_t wk_elems = (size_t)Adim * Hdim;          // 1,048,576
    // ws layout: keysb | Wkb | Spart[16][65536] | Cpart[16][32768]
    const size_t spart_off_f = (keys_elems + wk_elems) / 2;        // float offset
    const size_t cpart_off_f = spart_off_f + 16 * 65536;
    const size_t need = (keys_elems + wk_elems) * 2 + (16 * 65536 + 16 * 32768) * 4;

    if (ws_size >= need) {
        short* keysb = (short*)d_ws;
        short* Wkb = keysb + keys_elems;
        float* Spart = (float*)d_ws + spart_off_f;
        float* Cpart = (float*)d_ws + cpart_off_f;
        // fused prep: q | cvt Wk | cvt keys in one launch
        prep_kernel<<<dim3(4480), dim3(256), 0, stream>>>(query, Wq, ctx, Wk, Wkb, keys, keysb);
        fused_scores_bf16_8ph<<<dim3((Nb * Lseq / 256) * (Adim / 256)), dim3(512), 0, stream>>>(
            keysb, Wkb, ctx, v, Spart);
        softmax_part_kernel<<<dim3(Nb), dim3(256), 0, stream>>>(Spart, S);
        context_part_kernel<<<dim3(16, 32), dim3(256), 0, stream>>>(keysb, S, Cpart);
        context_reduce_kernel<<<dim3(Nb * Hdim / 256), dim3(256), 0, stream>>>(Cpart, ctx);
    } else {
        q_kernel<<<dim3((Nb * Adim) / 256), dim3(256), 0, stream>>>(query, Wq, ctx);
        hipMemsetAsync(S, 0, (size_t)Nb * Lseq * sizeof(float), stream);
        fused_scores_kernel<<<dim3((Nb * Lseq / 128) * (Adim / 128)), dim3(256), 0, stream>>>(
            keys, Wk, ctx, v, S);
        softmax_kernel<<<dim3(Nb), dim3(256), 0, stream>>>(S);
        hipMemsetAsync(ctx, 0, (size_t)Nb * Hdim * sizeof(float), stream);
        context_kernel<<<dim3(4, 8, Nb), dim3(256), 0, stream>>>(keys, S, ctx);
    }
}